// Round 1
// baseline (358.290 us; speedup 1.0000x reference)
//
#include <hip/hip_runtime.h>
#include <math.h>

#define H_IMG 768
#define W_IMG 1024
#define NPTS (H_IMG * W_IMG)
#define NITER 10
#define DIST_THR (100.0f / 15.0f)
#define NORMAL_THR 0.34f

// Workspace layout:
//   [0, NPTS*3*4)            float ref_grid[NPTS][3]
//   [NPTS*3*4, 2*NPTS*3*4)   float ref_nrm [NPTS][3]
//   then Ctrl block (8-byte aligned: 18874368 % 8 == 0)
struct Ctrl {
    double accum[NITER][32];   // per-iter: 21 JtJ upper-tri, 6 Jtr, r*r, w
    double x[6];               // current GN state
    float  pose[NITER + 1][12];// R row-major (9) + t (3)
    float  Kinv[9];
};

// ---------------------------------------------------------------- setup
__global__ void setup_kernel(const float* __restrict__ K, Ctrl* c) {
    int tid = threadIdx.x;
    double* ac = &c->accum[0][0];
    for (int i = tid; i < NITER * 32; i += blockDim.x) ac[i] = 0.0;
    if (tid < 6) c->x[tid] = 0.0;
    if (tid == 0) {
        float* p0 = c->pose[0];
        p0[0] = 1.f; p0[1] = 0.f; p0[2] = 0.f;
        p0[3] = 0.f; p0[4] = 1.f; p0[5] = 0.f;
        p0[6] = 0.f; p0[7] = 0.f; p0[8] = 1.f;
        p0[9] = 0.f; p0[10] = 0.f; p0[11] = 0.f;
        double a = K[0], b = K[1], cc = K[2];
        double d = K[3], e = K[4], f = K[5];
        double g = K[6], h = K[7], i = K[8];
        double det = a * (e * i - f * h) - b * (d * i - f * g) + cc * (d * h - e * g);
        double idet = 1.0 / det;
        c->Kinv[0] = (float)((e * i - f * h) * idet);
        c->Kinv[1] = (float)((cc * h - b * i) * idet);
        c->Kinv[2] = (float)((b * f - cc * e) * idet);
        c->Kinv[3] = (float)((f * g - d * i) * idet);
        c->Kinv[4] = (float)((a * i - cc * g) * idet);
        c->Kinv[5] = (float)((cc * d - a * f) * idet);
        c->Kinv[6] = (float)((d * h - e * g) * idet);
        c->Kinv[7] = (float)((b * g - a * h) * idet);
        c->Kinv[8] = (float)((a * e - b * d) * idet);
    }
}

// ---------------------------------------------------------------- backproject
__global__ __launch_bounds__(256) void backproject_kernel(const float* __restrict__ depth,
                                                          const Ctrl* __restrict__ c,
                                                          float* __restrict__ grid) {
    int i = blockIdx.x * blockDim.x + threadIdx.x;
    if (i >= NPTS) return;
    int v = i >> 10;        // W_IMG == 1024
    int u = i & 1023;
    float d = depth[i];
    float uf = (float)u, vf = (float)v;
    const float* Ki = c->Kinv;
    grid[3 * i + 0] = (Ki[0] * uf + Ki[1] * vf + Ki[2]) * d;
    grid[3 * i + 1] = (Ki[3] * uf + Ki[4] * vf + Ki[5]) * d;
    grid[3 * i + 2] = (Ki[6] * uf + Ki[7] * vf + Ki[8]) * d;
}

// ---------------------------------------------------------------- grid normals (np.gradient semantics)
__global__ __launch_bounds__(256) void normals_kernel(const float* __restrict__ grid,
                                                      float* __restrict__ nrm) {
    int i = blockIdx.x * blockDim.x + threadIdx.x;
    if (i >= NPTS) return;
    int v = i >> 10;
    int u = i & 1023;
    int um = (u > 0) ? u - 1 : 0;
    int up = (u < W_IMG - 1) ? u + 1 : W_IMG - 1;
    int vm = (v > 0) ? v - 1 : 0;
    int vp = (v < H_IMG - 1) ? v + 1 : H_IMG - 1;
    float su = (u > 0 && u < W_IMG - 1) ? 0.5f : 1.0f;
    float sv = (v > 0 && v < H_IMG - 1) ? 0.5f : 1.0f;
    int il = (v * W_IMG + um) * 3, ir = (v * W_IMG + up) * 3;
    int it = (vm * W_IMG + u) * 3, ib = (vp * W_IMG + u) * 3;
    float dux = (grid[ir + 0] - grid[il + 0]) * su;
    float duy = (grid[ir + 1] - grid[il + 1]) * su;
    float duz = (grid[ir + 2] - grid[il + 2]) * su;
    float dvx = (grid[ib + 0] - grid[it + 0]) * sv;
    float dvy = (grid[ib + 1] - grid[it + 1]) * sv;
    float dvz = (grid[ib + 2] - grid[it + 2]) * sv;
    float nx = duy * dvz - duz * dvy;
    float ny = duz * dvx - dux * dvz;
    float nz = dux * dvy - duy * dvx;
    float len = sqrtf(nx * nx + ny * ny + nz * nz + 1e-12f);
    nrm[3 * i + 0] = nx / len;
    nrm[3 * i + 1] = ny / len;
    nrm[3 * i + 2] = nz / len;
}

// ---------------------------------------------------------------- main reduction
__global__ __launch_bounds__(256) void icp_main(const float* __restrict__ tp,
                                                const float* __restrict__ tn,
                                                const float* __restrict__ grid,
                                                const float* __restrict__ nrm,
                                                const float* __restrict__ K,
                                                const float* __restrict__ pose,
                                                double* __restrict__ accum) {
    const float R0 = pose[0], R1 = pose[1], R2 = pose[2];
    const float R3 = pose[3], R4 = pose[4], R5 = pose[5];
    const float R6 = pose[6], R7 = pose[7], R8 = pose[8];
    const float t0 = pose[9], t1 = pose[10], t2 = pose[11];
    const float K0 = K[0], K1 = K[1], K2 = K[2];
    const float K3 = K[3], K4 = K[4], K5 = K[5];
    const float K6 = K[6], K7 = K[7], K8 = K[8];

    float acc[29];
#pragma unroll
    for (int k = 0; k < 29; ++k) acc[k] = 0.f;

    const int stride = gridDim.x * blockDim.x;
    for (int i = blockIdx.x * blockDim.x + threadIdx.x; i < NPTS; i += stride) {
        float p0 = tp[3 * i + 0], p1 = tp[3 * i + 1], p2 = tp[3 * i + 2];
        float n0 = tn[3 * i + 0], n1 = tn[3 * i + 1], n2 = tn[3 * i + 2];
        float d0 = p0 - t0, d1 = p1 - t1, d2 = p2 - t2;
        // pts_c = R^T (p - t)
        float pc0 = R0 * d0 + R3 * d1 + R6 * d2;
        float pc1 = R1 * d0 + R4 * d1 + R7 * d2;
        float pc2 = R2 * d0 + R5 * d1 + R8 * d2;
        // nrm_c = R^T n
        float nc0 = R0 * n0 + R3 * n1 + R6 * n2;
        float nc1 = R1 * n0 + R4 * n1 + R7 * n2;
        float nc2 = R2 * n0 + R5 * n1 + R8 * n2;
        // uvw = K pts_c
        float uu = K0 * pc0 + K1 * pc1 + K2 * pc2;
        float vv = K3 * pc0 + K4 * pc1 + K5 * pc2;
        float zz = K6 * pc0 + K7 * pc1 + K8 * pc2;
        float zs = (fabsf(zz) > 1e-8f) ? zz : 1e-8f;
        float uf = uu / zs, vf = vv / zs;
        bool valid = (uf > 0.f) && (uf < (float)W_IMG) && (vf > 0.f) && (vf < (float)H_IMG) && (zz > 1e-6f);
        int iu = (int)fminf(fmaxf(uf, 0.f), (float)(W_IMG - 1));
        int iv = (int)fminf(fmaxf(vf, 0.f), (float)(H_IMG - 1));
        int gi = ((iv << 10) + iu) * 3;
        float rg0 = grid[gi + 0], rg1 = grid[gi + 1], rg2 = grid[gi + 2];
        float rn0 = nrm[gi + 0], rn1 = nrm[gi + 1], rn2 = nrm[gi + 2];
        float dd0 = rg0 - pc0, dd1 = rg1 - pc1, dd2 = rg2 - pc2;
        float dist = sqrtf(dd0 * dd0 + dd1 * dd1 + dd2 * dd2 + 1e-12f);
        valid = valid && (dist < DIST_THR) && (rn0 * nc0 + rn1 * nc1 + rn2 * nc2 > NORMAL_THR);
        if (valid) {
            // ref_world = R rg + t
            float rw0 = R0 * rg0 + R1 * rg1 + R2 * rg2 + t0;
            float rw1 = R3 * rg0 + R4 * rg1 + R5 * rg2 + t1;
            float rw2 = R6 * rg0 + R7 * rg1 + R8 * rg2 + t2;
            float r = n0 * (rw0 - p0) + n1 * (rw1 - p1) + n2 * (rw2 - p2);
            float J[6];
            J[0] = rw1 * n2 - rw2 * n1;
            J[1] = rw2 * n0 - rw0 * n2;
            J[2] = rw0 * n1 - rw1 * n0;
            J[3] = n0; J[4] = n1; J[5] = n2;
            int cI = 0;
#pragma unroll
            for (int a = 0; a < 6; ++a) {
#pragma unroll
                for (int b = a; b < 6; ++b) acc[cI++] += J[a] * J[b];
            }
#pragma unroll
            for (int a = 0; a < 6; ++a) acc[21 + a] += J[a] * r;
            acc[27] += r * r;
            acc[28] += 1.f;
        }
    }

    // wave (64-lane) shuffle reduce
#pragma unroll
    for (int k = 0; k < 29; ++k) {
#pragma unroll
        for (int off = 32; off > 0; off >>= 1) acc[k] += __shfl_down(acc[k], off);
    }
    __shared__ float smem[4][29];
    int lane = threadIdx.x & 63;
    int wave = threadIdx.x >> 6;
    if (lane == 0) {
#pragma unroll
        for (int k = 0; k < 29; ++k) smem[wave][k] = acc[k];
    }
    __syncthreads();
    if (threadIdx.x < 29) {
        double s = (double)smem[0][threadIdx.x] + (double)smem[1][threadIdx.x]
                 + (double)smem[2][threadIdx.x] + (double)smem[3][threadIdx.x];
        atomicAdd(&accum[threadIdx.x], s);
    }
}

// ---------------------------------------------------------------- 6x6 solve + pose update
__global__ void icp_solve(Ctrl* c, const double* __restrict__ acc,
                          float* __restrict__ pose_next, float* __restrict__ out, int last) {
    if (threadIdx.x != 0 || blockIdx.x != 0) return;
    double M[6][7];
    int cI = 0;
    for (int a = 0; a < 6; ++a)
        for (int b = a; b < 6; ++b) {
            M[a][b] = acc[cI];
            M[b][a] = acc[cI];
            ++cI;
        }
    for (int a = 0; a < 6; ++a) M[a][6] = acc[21 + a];
    double cost = acc[27] / fmax(acc[28], 1.0);
    for (int d = 0; d < 6; ++d) M[d][d] += 1e-9;

    // Gaussian elimination with partial pivoting
    for (int col = 0; col < 6; ++col) {
        int piv = col;
        for (int r = col + 1; r < 6; ++r)
            if (fabs(M[r][col]) > fabs(M[piv][col])) piv = r;
        if (piv != col) {
            for (int k = col; k < 7; ++k) {
                double tmp = M[col][k]; M[col][k] = M[piv][k]; M[piv][k] = tmp;
            }
        }
        double p = M[col][col];
        for (int r = col + 1; r < 6; ++r) {
            double f = M[r][col] / p;
            for (int k = col; k < 7; ++k) M[r][k] -= f * M[col][k];
        }
    }
    double y[6];
    for (int i = 5; i >= 0; --i) {
        double s = M[i][6];
        for (int j = i + 1; j < 6; ++j) s -= M[i][j] * y[j];
        y[i] = s / M[i][i];
    }
    double xn[6];
    for (int i = 0; i < 6; ++i) {
        xn[i] = c->x[i] - y[i];
        c->x[i] = xn[i];
    }
    // so3_exp with the reference's epsilons
    double wx = xn[0], wy = xn[1], wz = xn[2];
    double th2 = wx * wx + wy * wy + wz * wz;
    double th = sqrt(th2 + 1e-12);
    double sA = sin(th) / th;
    double sB = (1.0 - cos(th)) / (th2 + 1e-12);
    double R[9];
    R[0] = 1.0 + sB * (-(wy * wy + wz * wz));
    R[1] = sA * (-wz) + sB * (wx * wy);
    R[2] = sA * ( wy) + sB * (wx * wz);
    R[3] = sA * ( wz) + sB * (wx * wy);
    R[4] = 1.0 + sB * (-(wx * wx + wz * wz));
    R[5] = sA * (-wx) + sB * (wy * wz);
    R[6] = sA * (-wy) + sB * (wx * wz);
    R[7] = sA * ( wx) + sB * (wy * wz);
    R[8] = 1.0 + sB * (-(wx * wx + wy * wy));
    for (int k = 0; k < 9; ++k) pose_next[k] = (float)R[k];
    pose_next[9]  = (float)xn[3];
    pose_next[10] = (float)xn[4];
    pose_next[11] = (float)xn[5];
    if (last) {
        out[0]  = (float)R[0]; out[1]  = (float)R[1]; out[2]  = (float)R[2]; out[3]  = (float)xn[3];
        out[4]  = (float)R[3]; out[5]  = (float)R[4]; out[6]  = (float)R[5]; out[7]  = (float)xn[4];
        out[8]  = (float)R[6]; out[9]  = (float)R[7]; out[10] = (float)R[8]; out[11] = (float)xn[5];
        out[12] = 0.f; out[13] = 0.f; out[14] = 0.f; out[15] = 1.f;
        out[16] = (float)cost;
    }
}

// ---------------------------------------------------------------- launch
extern "C" void kernel_launch(void* const* d_in, const int* in_sizes, int n_in,
                              void* d_out, int out_size, void* d_ws, size_t ws_size,
                              hipStream_t stream) {
    const float* ref_depth      = (const float*)d_in[0];
    const float* target_pts     = (const float*)d_in[1];
    const float* target_normals = (const float*)d_in[2];
    const float* K              = (const float*)d_in[3];
    float* out = (float*)d_out;
    char* ws = (char*)d_ws;

    const size_t grid_bytes = (size_t)NPTS * 3 * sizeof(float);
    float* ref_grid = (float*)ws;
    float* ref_nrm  = (float*)(ws + grid_bytes);
    Ctrl*  ctrl     = (Ctrl*)(ws + 2 * grid_bytes);

    setup_kernel<<<1, 256, 0, stream>>>(K, ctrl);
    backproject_kernel<<<NPTS / 256, 256, 0, stream>>>(ref_depth, ctrl, ref_grid);
    normals_kernel<<<NPTS / 256, 256, 0, stream>>>(ref_grid, ref_nrm);
    for (int it = 0; it < NITER; ++it) {
        icp_main<<<512, 256, 0, stream>>>(target_pts, target_normals, ref_grid, ref_nrm, K,
                                          ctrl->pose[it], &ctrl->accum[it][0]);
        icp_solve<<<1, 64, 0, stream>>>(ctrl, &ctrl->accum[it][0],
                                        ctrl->pose[it + 1], out, it == NITER - 1 ? 1 : 0);
    }
}